// Round 4
// baseline (779.752 us; speedup 1.0000x reference)
//
#include <hip/hip_runtime.h>
#include <stdint.h>

// ---------------------------------------------------------------------------
// MHA forward, MI355X/gfx950.
// Reference: proj(q,k,v) -> scores=QK^T/8 -> softmax (FULL row) -> mask-fill
// (post-softmax, -1e-9 where mask==0) -> PV -> out @ wout^T.   All fp32.
//
// Split-bf16 (hi/lo) MFMA everywhere: a*b ~= ahi*bhi + ahi*blo + alo*bhi.
// The -1e-9 masked-fill value is approximated by 0 (contribution ~3e-8 abs).
//
// R4 changes (attn was 320us @ 23% occupancy, grid-capped at 2 blocks/CU):
//  - attn QBLK 128->64: grid 512->1024 blocks = 4 blocks/CU = 16 waves/CU.
//  - mask precomputed int32 -> bf16 {0,1} (8 MB, dead ws region), multiplied
//    into P instead of int cmp+select (halves mask HBM bytes).
// ---------------------------------------------------------------------------

#define BATCH  2
#define S_LEN  2048
#define DMODEL 1024
#define NH     16
#define HD     64

typedef __bf16 bf16_t;
typedef short  short8 __attribute__((ext_vector_type(8)));   // 8 x bf16 bits
typedef float  f32x4  __attribute__((ext_vector_type(4)));

#define AS1 __attribute__((address_space(1)))
#define AS3 __attribute__((address_space(3)))

static constexpr size_t MB = (size_t)1 << 20;
static constexpr size_t WS_REQUIRED = 112 * MB;
// Workspace layout (byte offsets). High-water: 112 MB.
//  0..48MB   : input splits qx/kx/vx (hi,lo)   [dead after projections]
//  0..16MB   : (reused) attention output O (hi,lo)
//  16..24MB  : (reused) mask as bf16 {0,1}     [written after projections]
//  48..64MB  : weight splits wq,wk,wv,wout (hi,lo)
//  64..112MB : Q (pre-scaled 1/8), K as [B,H,S,hd]; V transposed [B,H,hd,S]
#define OFF_XHI(z)  ((size_t)(z) * 16 * MB)
#define OFF_XLO(z)  (OFF_XHI(z) + 8 * MB)
#define OFF_WHI(z)  (48 * MB + (size_t)(z) * 4 * MB)
#define OFF_WLO(z)  (OFF_WHI(z) + 2 * MB)
#define OFF_PHI(z)  (64 * MB + (size_t)(z) * 16 * MB)   // z=0:Q 1:K 2:VT
#define OFF_PLO(z)  (OFF_PHI(z) + 8 * MB)
#define OFF_OHI     ((size_t)0)
#define OFF_OLO     (8 * MB)
#define OFF_MASKB   (16 * MB)

__device__ __forceinline__ f32x4 mfma_bf16(short8 a, short8 b, f32x4 c) {
    return __builtin_amdgcn_mfma_f32_16x16x32_bf16(a, b, c, 0, 0, 0);
}

__device__ __forceinline__ short8 ld8(const bf16_t* p) {
    return *reinterpret_cast<const short8*>(p);
}

// ---------------------------------------------------------------------------
// fp32 -> (bf16 hi, bf16 lo) split conversion, vectorized float4.
// ---------------------------------------------------------------------------
__global__ void cvt_split_kernel(const float* __restrict__ x,
                                 bf16_t* __restrict__ hi, bf16_t* __restrict__ lo,
                                 int n) {
    int i = (blockIdx.x * blockDim.x + threadIdx.x) * 4;
    if (i >= n) return;
    const float4 v = *reinterpret_cast<const float4*>(x + i);
    float s[4] = {v.x, v.y, v.z, v.w};
    ushort hbits[4], lbits[4];
#pragma unroll
    for (int j = 0; j < 4; j++) {
        bf16_t hh = (bf16_t)s[j];
        bf16_t ll = (bf16_t)(s[j] - (float)hh);
        hbits[j] = __builtin_bit_cast(ushort, hh);
        lbits[j] = __builtin_bit_cast(ushort, ll);
    }
    *reinterpret_cast<ushort4*>(hi + i) = ushort4{hbits[0], hbits[1], hbits[2], hbits[3]};
    *reinterpret_cast<ushort4*>(lo + i) = ushort4{lbits[0], lbits[1], lbits[2], lbits[3]};
}

// mask int32 -> bf16 {0,1}
__global__ void cvt_mask_kernel(const int* __restrict__ m, bf16_t* __restrict__ mb, int n) {
    int i = (blockIdx.x * blockDim.x + threadIdx.x) * 4;
    if (i >= n) return;
    const int4 v = *reinterpret_cast<const int4*>(m + i);
    int s[4] = {v.x, v.y, v.z, v.w};
    ushort b[4];
#pragma unroll
    for (int j = 0; j < 4; j++) {
        bf16_t t = (bf16_t)(s[j] ? 1.0f : 0.0f);
        b[j] = __builtin_bit_cast(ushort, t);
    }
    *reinterpret_cast<ushort4*>(mb + i) = ushort4{b[0], b[1], b[2], b[3]};
}

// ---------------------------------------------------------------------------
// Split-bf16 GEMM, C = A @ B^T (both operands K-contiguous), K=1024 done as
// 3 segments {(Ahi,Bhi),(Ahi,Blo),(Alo,Bhi)}.  128x128 tile, BK=32,
// 256 threads = 4 waves (2x2), each wave 64x64 = 4x4 16x16x32 frags.
// FINAL=0: grid.z picks q/k/v; epilogue writes head-split hi/lo (Q scaled
//          1/8; V transposed).  FINAL=1: output projection, fp32 -> d_out.
// ---------------------------------------------------------------------------
template <int FINAL>
__global__ __launch_bounds__(256, 2) void gemm_split_kernel(char* __restrict__ ws,
                                                            float* __restrict__ fout) {
    __shared__ __align__(16) bf16_t As[128 * 32];
    __shared__ __align__(16) bf16_t Bs[128 * 32];

    const int z = FINAL ? 3 : blockIdx.z;
    const bf16_t* Ahi = FINAL ? (const bf16_t*)(ws + OFF_OHI) : (const bf16_t*)(ws + OFF_XHI(z));
    const bf16_t* Alo = FINAL ? (const bf16_t*)(ws + OFF_OLO) : (const bf16_t*)(ws + OFF_XLO(z));
    const bf16_t* Bhi = (const bf16_t*)(ws + OFF_WHI(z));
    const bf16_t* Blo = (const bf16_t*)(ws + OFF_WLO(z));
    bf16_t* Ohi = FINAL ? nullptr : (bf16_t*)(ws + OFF_PHI(z));
    bf16_t* Olo = FINAL ? nullptr : (bf16_t*)(ws + OFF_PLO(z));
    const float scale = (!FINAL && z == 0) ? 0.125f : 1.0f;  // 1/sqrt(hd) folded into Q

    const int tid = threadIdx.x;
    const int lane = tid & 63, w = tid >> 6;
    const int wr = w >> 1, wc = w & 1;
    const int fr = lane & 15, fg = lane >> 4;
    const int m0 = blockIdx.x * 128, n0 = blockIdx.y * 128;
    const int K = 1024;

    const bf16_t* Aseg[3] = {Ahi, Ahi, Alo};
    const bf16_t* Bseg[3] = {Bhi, Blo, Bhi};

    f32x4 acc[4][4];
#pragma unroll
    for (int i = 0; i < 4; i++)
#pragma unroll
        for (int j = 0; j < 4; j++) acc[i][j] = f32x4{0.f, 0.f, 0.f, 0.f};

    AS3 bf16_t* asA = (AS3 bf16_t*)As;
    AS3 bf16_t* asB = (AS3 bf16_t*)Bs;

#pragma unroll 1
    for (int seg = 0; seg < 3; ++seg) {
        const bf16_t* Ab = Aseg[seg];
        const bf16_t* Bb = Bseg[seg];
#pragma unroll 1
        for (int ks = 0; ks < K; ks += 32) {
            __syncthreads();  // previous compute done before restaging
#pragma unroll
            for (int i = 0; i < 2; i++) {
                // chunk c covers 16B: LDS byte c*16; global row c/4, 16B col (c&3)*16
                const int c = i * 256 + tid;
                const int row = c >> 2;
                const int ce = (c & 3) * 8;  // element offset within row
                __builtin_amdgcn_global_load_lds((const AS1 void*)(Ab + (size_t)(m0 + row) * K + ks + ce),
                                                 (AS3 void*)(asA + (size_t)(i * 256 + w * 64) * 8),
                                                 16, 0, 0);
                __builtin_amdgcn_global_load_lds((const AS1 void*)(Bb + (size_t)(n0 + row) * K + ks + ce),
                                                 (AS3 void*)(asB + (size_t)(i * 256 + w * 64) * 8),
                                                 16, 0, 0);
            }
            __syncthreads();  // staging visible (syncthreads drains vmcnt)

            short8 af[4], bfr[4];
#pragma unroll
            for (int i = 0; i < 4; i++) {
                af[i]  = ld8(&As[(wr * 64 + i * 16 + fr) * 32 + fg * 8]);
                bfr[i] = ld8(&Bs[(wc * 64 + i * 16 + fr) * 32 + fg * 8]);
            }
#pragma unroll
            for (int i = 0; i < 4; i++)
#pragma unroll
                for (int j = 0; j < 4; j++)
                    acc[i][j] = mfma_bf16(af[i], bfr[j], acc[i][j]);
        }
    }

    // Epilogue. C/D frag: col = lane&15, row = (lane>>4)*4 + reg  [HW-verified]
#pragma unroll
    for (int i = 0; i < 4; i++) {
#pragma unroll
        for (int j = 0; j < 4; j++) {
            const int ncol = n0 + wc * 64 + j * 16 + fr;
#pragma unroll
            for (int r = 0; r < 4; r++) {
                const int m = m0 + wr * 64 + i * 16 + fg * 4 + r;
                const float val = acc[i][j][r] * scale;
                if (FINAL) {
                    fout[(size_t)m * DMODEL + ncol] = val;
                } else {
                    const bf16_t h = (bf16_t)val;
                    const bf16_t l = (bf16_t)(val - (float)h);
                    const int b = m >> 11, s = m & (S_LEN - 1);
                    const int hh = ncol >> 6, d = ncol & (HD - 1);
                    size_t idx;
                    if (z == 2) idx = ((size_t)(b * NH + hh) * HD + d) * S_LEN + s;      // VT [B,H,hd,S]
                    else        idx = ((size_t)(b * NH + hh) * S_LEN + s) * HD + d;      // [B,H,S,hd]
                    Ohi[idx] = h;
                    Olo[idx] = l;
                }
            }
        }
    }
}

// ---------------------------------------------------------------------------
// Flash attention with post-softmax mask.  Grid: (S/64, B*H), 256 threads.
// 4 independent waves/block, each owns 16 q-rows; no cross-wave coupling, no
// __syncthreads.  4 blocks/CU (16 waves/CU) for latency hiding.
// K/V read directly from global (L2-resident per (b,h)).
// P transposed D-layout -> A-layout via per-wave LDS stripe (row stride 72).
// ---------------------------------------------------------------------------
__global__ __launch_bounds__(256, 4) void attn_kernel(char* __restrict__ ws) {
    __shared__ __align__(16) bf16_t Ph[64 * 72];
    __shared__ __align__(16) bf16_t Pl[64 * 72];

    const bf16_t* Qhi = (const bf16_t*)(ws + OFF_PHI(0));
    const bf16_t* Qlo = (const bf16_t*)(ws + OFF_PLO(0));
    const bf16_t* Khi = (const bf16_t*)(ws + OFF_PHI(1));
    const bf16_t* Klo = (const bf16_t*)(ws + OFF_PLO(1));
    const bf16_t* Vhi = (const bf16_t*)(ws + OFF_PHI(2));
    const bf16_t* Vlo = (const bf16_t*)(ws + OFF_PLO(2));
    const bf16_t* Mb  = (const bf16_t*)(ws + OFF_MASKB);
    bf16_t* Ohi = (bf16_t*)(ws + OFF_OHI);
    bf16_t* Olo = (bf16_t*)(ws + OFF_OLO);

    const int tid = threadIdx.x, lane = tid & 63, w = tid >> 6;
    const int fr = lane & 15, fg = lane >> 4;
    const int bh = blockIdx.y;
    const int q0 = blockIdx.x * 64;
    const size_t qkBase = (size_t)bh * S_LEN * HD;
    const size_t vtBase = (size_t)bh * HD * S_LEN;

    // Q fragments (Q pre-scaled by 1/8 at projection epilogue)
    short8 qh[2], ql[2];
#pragma unroll
    for (int kc = 0; kc < 2; kc++) {
        const size_t off = qkBase + (size_t)(q0 + w * 16 + fr) * HD + kc * 32 + fg * 8;
        qh[kc] = ld8(Qhi + off);
        ql[kc] = ld8(Qlo + off);
    }

    f32x4 acco[4];
#pragma unroll
    for (int df = 0; df < 4; df++) acco[df] = f32x4{0.f, 0.f, 0.f, 0.f};
    float mrun[4], lrun[4];
#pragma unroll
    for (int r = 0; r < 4; r++) { mrun[r] = -__builtin_inff(); lrun[r] = 0.f; }

#pragma unroll 1
    for (int k0 = 0; k0 < S_LEN; k0 += 64) {
        // ---- scores: S = Q K^T (already scaled), split 3-MFMA, hd = 2 x K32
        f32x4 sacc[4];
#pragma unroll
        for (int cf = 0; cf < 4; cf++) sacc[cf] = f32x4{0.f, 0.f, 0.f, 0.f};
#pragma unroll
        for (int cf = 0; cf < 4; cf++) {
            const int kk = k0 + cf * 16 + fr;
#pragma unroll
            for (int kc = 0; kc < 2; kc++) {
                const size_t off = qkBase + (size_t)kk * HD + kc * 32 + fg * 8;
                const short8 kh = ld8(Khi + off);
                const short8 kl = ld8(Klo + off);
                sacc[cf] = mfma_bf16(qh[kc], kh, sacc[cf]);
                sacc[cf] = mfma_bf16(qh[kc], kl, sacc[cf]);
                sacc[cf] = mfma_bf16(ql[kc], kh, sacc[cf]);
            }
        }

        // previous tile's PV ds_reads complete before overwriting P stripe
        asm volatile("s_waitcnt lgkmcnt(0)" ::: "memory");

        // ---- online softmax over FULL row (mask is post-softmax), then
        //      write masked P (hi/lo) into this wave's LDS stripe.
#pragma unroll
        for (int r = 0; r < 4; r++) {
            float mx = fmaxf(fmaxf(sacc[0][r], sacc[1][r]),
                             fmaxf(sacc[2][r], sacc[3][r]));
            mx = fmaxf(mx, __shfl_xor(mx, 1, 64));
            mx = fmaxf(mx, __shfl_xor(mx, 2, 64));
            mx = fmaxf(mx, __shfl_xor(mx, 4, 64));
            mx = fmaxf(mx, __shfl_xor(mx, 8, 64));
            const float mnew = fmaxf(mrun[r], mx);
            const float alpha = __expf(mrun[r] - mnew);
            mrun[r] = mnew;
            float psum = 0.f;
#pragma unroll
            for (int cf = 0; cf < 4; cf++) {
                const float p = __expf(sacc[cf][r] - mnew);
                sacc[cf][r] = p;
                psum += p;
            }
            psum += __shfl_xor(psum, 1, 64);
            psum += __shfl_xor(psum, 2, 64);
            psum += __shfl_xor(psum, 4, 64);
            psum += __shfl_xor(psum, 8, 64);
            lrun[r] = lrun[r] * alpha + psum;
#pragma unroll
            for (int df = 0; df < 4; df++) acco[df][r] *= alpha;

            const int qrl = w * 16 + fg * 4 + r;
            const size_t mrow = (size_t)(q0 + qrl) * S_LEN + k0;
#pragma unroll
            for (int cf = 0; cf < 4; cf++) {
                const int kcol = cf * 16 + fr;
                const float mv = (float)Mb[mrow + kcol];      // {0,1}
                const float pm = sacc[cf][r] * mv;
                const bf16_t h = (bf16_t)pm;
                Ph[qrl * 72 + kcol] = h;
                Pl[qrl * 72 + kcol] = (bf16_t)(pm - (float)h);
            }
        }

        // P writes land before A-layout re-read (same wave, in-order DS)
        asm volatile("s_waitcnt lgkmcnt(0)" ::: "memory");

        // ---- PV accumulate: A = masked P (LDS), B = V^T (global, K-contig)
#pragma unroll
        for (int kc2 = 0; kc2 < 2; kc2++) {
            const short8 pah = ld8(&Ph[(w * 16 + fr) * 72 + kc2 * 32 + fg * 8]);
            const short8 pal = ld8(&Pl[(w * 16 + fr) * 72 + kc2 * 32 + fg * 8]);
#pragma unroll
            for (int df = 0; df < 4; df++) {
                const size_t voff = vtBase + (size_t)(df * 16 + fr) * S_LEN + k0 + kc2 * 32 + fg * 8;
                const short8 vh = ld8(Vhi + voff);
                const short8 vl = ld8(Vlo + voff);
                acco[df] = mfma_bf16(pah, vh, acco[df]);
                acco[df] = mfma_bf16(pah, vl, acco[df]);
                acco[df] = mfma_bf16(pal, vh, acco[df]);
            }
        }
    }

    // ---- epilogue: normalize, split to hi/lo, store O as [B,S,D]
    const int b = bh >> 4, hh = bh & (NH - 1);
#pragma unroll
    for (int r = 0; r < 4; r++) {
        const int qrow = q0 + w * 16 + fg * 4 + r;
        const float inv = 1.0f / lrun[r];
#pragma unroll
        for (int df = 0; df < 4; df++) {
            const float o = acco[df][r] * inv;
            const bf16_t h = (bf16_t)o;
            const size_t idx = ((size_t)b * S_LEN + qrow) * DMODEL + hh * HD + df * 16 + fr;
            Ohi[idx] = h;
            Olo[idx] = (bf16_t)(o - (float)h);
        }
    }
}

// ---------------------------------------------------------------------------
extern "C" void kernel_launch(void* const* d_in, const int* in_sizes, int n_in,
                              void* d_out, int out_size, void* d_ws, size_t ws_size,
                              hipStream_t stream) {
    (void)in_sizes; (void)n_in; (void)out_size;
    if (ws_size < WS_REQUIRED) return;  // clean incorrect-output signal, not an OOB crash

    const float* q    = (const float*)d_in[0];
    const float* k    = (const float*)d_in[1];
    const float* v    = (const float*)d_in[2];
    const int*   mask = (const int*)  d_in[3];
    const float* wq   = (const float*)d_in[4];
    const float* wk   = (const float*)d_in[5];
    const float* wv   = (const float*)d_in[6];
    const float* wout = (const float*)d_in[7];
    char* ws = (char*)d_ws;
    float* out = (float*)d_out;

    const size_t nX = (size_t)BATCH * S_LEN * DMODEL;  // 4,194,304
    const size_t nW = (size_t)DMODEL * DMODEL;         // 1,048,576
    const size_t nM = (size_t)S_LEN * S_LEN;           // 4,194,304
    const dim3 blk(256);

    // fp32 -> hi/lo splits
    cvt_split_kernel<<<dim3(nX / 1024), blk, 0, stream>>>(q, (bf16_t*)(ws + OFF_XHI(0)), (bf16_t*)(ws + OFF_XLO(0)), (int)nX);
    cvt_split_kernel<<<dim3(nX / 1024), blk, 0, stream>>>(k, (bf16_t*)(ws + OFF_XHI(1)), (bf16_t*)(ws + OFF_XLO(1)), (int)nX);
    cvt_split_kernel<<<dim3(nX / 1024), blk, 0, stream>>>(v, (bf16_t*)(ws + OFF_XHI(2)), (bf16_t*)(ws + OFF_XLO(2)), (int)nX);
    cvt_split_kernel<<<dim3(nW / 1024), blk, 0, stream>>>(wq,   (bf16_t*)(ws + OFF_WHI(0)), (bf16_t*)(ws + OFF_WLO(0)), (int)nW);
    cvt_split_kernel<<<dim3(nW / 1024), blk, 0, stream>>>(wk,   (bf16_t*)(ws + OFF_WHI(1)), (bf16_t*)(ws + OFF_WLO(1)), (int)nW);
    cvt_split_kernel<<<dim3(nW / 1024), blk, 0, stream>>>(wv,   (bf16_t*)(ws + OFF_WHI(2)), (bf16_t*)(ws + OFF_WLO(2)), (int)nW);
    cvt_split_kernel<<<dim3(nW / 1024), blk, 0, stream>>>(wout, (bf16_t*)(ws + OFF_WHI(3)), (bf16_t*)(ws + OFF_WLO(3)), (int)nW);

    // q/k/v projections (z = 0/1/2), head-split epilogues
    gemm_split_kernel<0><<<dim3(32, 8, 3), blk, 0, stream>>>(ws, nullptr);

    // mask -> bf16 {0,1} into region freed by the input splits (stream-ordered
    // after the projections, which are the last readers of that region)
    cvt_mask_kernel<<<dim3(nM / 1024), blk, 0, stream>>>(mask, (bf16_t*)(ws + OFF_MASKB), (int)nM);

    // flash attention with post-softmax mask
    attn_kernel<<<dim3(S_LEN / 64, BATCH * NH), blk, 0, stream>>>(ws);

    // output projection -> d_out (fp32)
    gemm_split_kernel<1><<<dim3(32, 8, 1), blk, 0, stream>>>(ws, out);
}

// Round 5
// 711.096 us; speedup vs baseline: 1.0965x; 1.0965x over previous
//
#include <hip/hip_runtime.h>
#include <stdint.h>

// ---------------------------------------------------------------------------
// MHA forward, MI355X/gfx950.
// Reference: proj(q,k,v) -> scores=QK^T/8 -> softmax (FULL row) -> mask-fill
// (post-softmax, -1e-9 where mask==0) -> PV -> out @ wout^T.   All fp32.
//
// Split-bf16 (hi/lo) MFMA everywhere: a*b ~= ahi*bhi + ahi*blo + alo*bhi.
// The -1e-9 masked-fill value is approximated by 0 (contribution ~3e-8 abs).
//
// R5: R4's QBLK=64 + launch_bounds(256,4) squeezed VGPR 120->64 and the
// compiler serialized loads (MfmaUtil 13->8%, 1.6x slower). Revert to R3
// attn geometry (QBLK=128, 4 waves x 32 rows, full ILP) and get parallelism
// via flash-decoding: split S into 2 k-chunks of 1024 -> 1024 blocks
// (3-4/CU), unnormalized fp32 partials + (m,l), then a merge kernel.
// ---------------------------------------------------------------------------

#define BATCH  2
#define S_LEN  2048
#define DMODEL 1024
#define NH     16
#define HD     64
#define NCHUNK 2
#define KCHUNK (S_LEN / NCHUNK)

typedef __bf16 bf16_t;
typedef short  short8 __attribute__((ext_vector_type(8)));   // 8 x bf16 bits
typedef float  f32x4  __attribute__((ext_vector_type(4)));

#define AS1 __attribute__((address_space(1)))
#define AS3 __attribute__((address_space(3)))

static constexpr size_t MB = (size_t)1 << 20;
static constexpr size_t WS_REQUIRED = 112 * MB;
// Workspace layout (byte offsets). High-water: 112 MB.
//  0..16MB   : qx splits (hi,lo) [projection inputs] -> then O_part chunk0 (fp32)
//  16..24MB  : kx hi (first half) -> then mask bf16 {0,1}
//  24..40MB  : kx (rest)/vx  -> then O_part chunk1 (fp32)
//  40..41MB  : m/l per chunk (4 x 64K floats)
//  48..64MB  : weight splits wq,wk,wv,wout (hi,lo)
//  64..80MB  : Q hi/lo (pre-scaled 1/8) -> after attn: O hi/lo (merge output)
//  80..96MB  : K hi/lo as [B,H,S,hd]
//  96..112MB : V^T hi/lo as [B,H,hd,S]
#define OFF_XHI(z)  ((size_t)(z) * 16 * MB)
#define OFF_XLO(z)  (OFF_XHI(z) + 8 * MB)
#define OFF_WHI(z)  (48 * MB + (size_t)(z) * 4 * MB)
#define OFF_WLO(z)  (OFF_WHI(z) + 2 * MB)
#define OFF_PHI(z)  (64 * MB + (size_t)(z) * 16 * MB)   // z=0:Q 1:K 2:VT
#define OFF_PLO(z)  (OFF_PHI(z) + 8 * MB)
#define OFF_MASKB   (16 * MB)
#define OFF_OP(c)   ((size_t)(c) * 24 * MB)             // fp32 partials: c0@0, c1@24MB (16MB each)
#define OFF_ML      (40 * MB)                           // m[c] @ +c*512K, l[c] @ +c*512K+256K

__device__ __forceinline__ f32x4 mfma_bf16(short8 a, short8 b, f32x4 c) {
    return __builtin_amdgcn_mfma_f32_16x16x32_bf16(a, b, c, 0, 0, 0);
}

__device__ __forceinline__ short8 ld8(const bf16_t* p) {
    return *reinterpret_cast<const short8*>(p);
}

// ---------------------------------------------------------------------------
// fp32 -> (bf16 hi, bf16 lo) split conversion, vectorized float4.
// ---------------------------------------------------------------------------
__global__ void cvt_split_kernel(const float* __restrict__ x,
                                 bf16_t* __restrict__ hi, bf16_t* __restrict__ lo,
                                 int n) {
    int i = (blockIdx.x * blockDim.x + threadIdx.x) * 4;
    if (i >= n) return;
    const float4 v = *reinterpret_cast<const float4*>(x + i);
    float s[4] = {v.x, v.y, v.z, v.w};
    ushort hbits[4], lbits[4];
#pragma unroll
    for (int j = 0; j < 4; j++) {
        bf16_t hh = (bf16_t)s[j];
        bf16_t ll = (bf16_t)(s[j] - (float)hh);
        hbits[j] = __builtin_bit_cast(ushort, hh);
        lbits[j] = __builtin_bit_cast(ushort, ll);
    }
    *reinterpret_cast<ushort4*>(hi + i) = ushort4{hbits[0], hbits[1], hbits[2], hbits[3]};
    *reinterpret_cast<ushort4*>(lo + i) = ushort4{lbits[0], lbits[1], lbits[2], lbits[3]};
}

// mask int32 -> bf16 {0,1}
__global__ void cvt_mask_kernel(const int* __restrict__ m, bf16_t* __restrict__ mb, int n) {
    int i = (blockIdx.x * blockDim.x + threadIdx.x) * 4;
    if (i >= n) return;
    const int4 v = *reinterpret_cast<const int4*>(m + i);
    int s[4] = {v.x, v.y, v.z, v.w};
    ushort b[4];
#pragma unroll
    for (int j = 0; j < 4; j++) {
        bf16_t t = (bf16_t)(s[j] ? 1.0f : 0.0f);
        b[j] = __builtin_bit_cast(ushort, t);
    }
    *reinterpret_cast<ushort4*>(mb + i) = ushort4{b[0], b[1], b[2], b[3]};
}

// ---------------------------------------------------------------------------
// Split-bf16 GEMM, C = A @ B^T (both operands K-contiguous), K=1024 done as
// 3 segments {(Ahi,Bhi),(Ahi,Blo),(Alo,Bhi)}.  128x128 tile, BK=32,
// 256 threads = 4 waves (2x2), each wave 64x64 = 4x4 16x16x32 frags.
// FINAL=0: grid.z picks q/k/v; epilogue writes head-split hi/lo (Q scaled
//          1/8; V transposed).  FINAL=1: output projection (A = merged O at
//          the old Q slot), fp32 -> d_out.
// ---------------------------------------------------------------------------
template <int FINAL>
__global__ __launch_bounds__(256, 2) void gemm_split_kernel(char* __restrict__ ws,
                                                            float* __restrict__ fout) {
    __shared__ __align__(16) bf16_t As[128 * 32];
    __shared__ __align__(16) bf16_t Bs[128 * 32];

    const int z = FINAL ? 3 : blockIdx.z;
    const bf16_t* Ahi = FINAL ? (const bf16_t*)(ws + OFF_PHI(0)) : (const bf16_t*)(ws + OFF_XHI(z));
    const bf16_t* Alo = FINAL ? (const bf16_t*)(ws + OFF_PLO(0)) : (const bf16_t*)(ws + OFF_XLO(z));
    const bf16_t* Bhi = (const bf16_t*)(ws + OFF_WHI(z));
    const bf16_t* Blo = (const bf16_t*)(ws + OFF_WLO(z));
    bf16_t* Ohi = FINAL ? nullptr : (bf16_t*)(ws + OFF_PHI(z));
    bf16_t* Olo = FINAL ? nullptr : (bf16_t*)(ws + OFF_PLO(z));
    const float scale = (!FINAL && z == 0) ? 0.125f : 1.0f;  // 1/sqrt(hd) folded into Q

    const int tid = threadIdx.x;
    const int lane = tid & 63, w = tid >> 6;
    const int wr = w >> 1, wc = w & 1;
    const int fr = lane & 15, fg = lane >> 4;
    const int m0 = blockIdx.x * 128, n0 = blockIdx.y * 128;
    const int K = 1024;

    const bf16_t* Aseg[3] = {Ahi, Ahi, Alo};
    const bf16_t* Bseg[3] = {Bhi, Blo, Bhi};

    f32x4 acc[4][4];
#pragma unroll
    for (int i = 0; i < 4; i++)
#pragma unroll
        for (int j = 0; j < 4; j++) acc[i][j] = f32x4{0.f, 0.f, 0.f, 0.f};

    AS3 bf16_t* asA = (AS3 bf16_t*)As;
    AS3 bf16_t* asB = (AS3 bf16_t*)Bs;

#pragma unroll 1
    for (int seg = 0; seg < 3; ++seg) {
        const bf16_t* Ab = Aseg[seg];
        const bf16_t* Bb = Bseg[seg];
#pragma unroll 1
        for (int ks = 0; ks < K; ks += 32) {
            __syncthreads();  // previous compute done before restaging
#pragma unroll
            for (int i = 0; i < 2; i++) {
                // chunk c covers 16B: LDS byte c*16; global row c/4, 16B col (c&3)*16
                const int c = i * 256 + tid;
                const int row = c >> 2;
                const int ce = (c & 3) * 8;  // element offset within row
                __builtin_amdgcn_global_load_lds((const AS1 void*)(Ab + (size_t)(m0 + row) * K + ks + ce),
                                                 (AS3 void*)(asA + (size_t)(i * 256 + w * 64) * 8),
                                                 16, 0, 0);
                __builtin_amdgcn_global_load_lds((const AS1 void*)(Bb + (size_t)(n0 + row) * K + ks + ce),
                                                 (AS3 void*)(asB + (size_t)(i * 256 + w * 64) * 8),
                                                 16, 0, 0);
            }
            __syncthreads();  // staging visible (syncthreads drains vmcnt)

            short8 af[4], bfr[4];
#pragma unroll
            for (int i = 0; i < 4; i++) {
                af[i]  = ld8(&As[(wr * 64 + i * 16 + fr) * 32 + fg * 8]);
                bfr[i] = ld8(&Bs[(wc * 64 + i * 16 + fr) * 32 + fg * 8]);
            }
#pragma unroll
            for (int i = 0; i < 4; i++)
#pragma unroll
                for (int j = 0; j < 4; j++)
                    acc[i][j] = mfma_bf16(af[i], bfr[j], acc[i][j]);
        }
    }

    // Epilogue. C/D frag: col = lane&15, row = (lane>>4)*4 + reg  [HW-verified]
#pragma unroll
    for (int i = 0; i < 4; i++) {
#pragma unroll
        for (int j = 0; j < 4; j++) {
            const int ncol = n0 + wc * 64 + j * 16 + fr;
#pragma unroll
            for (int r = 0; r < 4; r++) {
                const int m = m0 + wr * 64 + i * 16 + fg * 4 + r;
                const float val = acc[i][j][r] * scale;
                if (FINAL) {
                    fout[(size_t)m * DMODEL + ncol] = val;
                } else {
                    const bf16_t h = (bf16_t)val;
                    const bf16_t l = (bf16_t)(val - (float)h);
                    const int b = m >> 11, s = m & (S_LEN - 1);
                    const int hh = ncol >> 6, d = ncol & (HD - 1);
                    size_t idx;
                    if (z == 2) idx = ((size_t)(b * NH + hh) * HD + d) * S_LEN + s;      // VT [B,H,hd,S]
                    else        idx = ((size_t)(b * NH + hh) * S_LEN + s) * HD + d;      // [B,H,S,hd]
                    Ohi[idx] = h;
                    Olo[idx] = l;
                }
            }
        }
    }
}

// ---------------------------------------------------------------------------
// Flash attention, k-chunked (flash-decoding).  Grid: (S/128, B*H, NCHUNK),
// 256 threads = 4 independent waves x 32 q-rows (R3 geometry, full ILP).
// Each block processes k in [z*1024, z*1024+1024), keeps online (m,l) and
// unnormalized fp32 partial O; merge_kernel combines chunks.
// P transposed D-layout -> A-layout via per-wave LDS stripe (row stride 72).
// ---------------------------------------------------------------------------
__global__ __launch_bounds__(256, 3) void attn_kernel(char* __restrict__ ws) {
    __shared__ __align__(16) bf16_t Ph[128 * 72];
    __shared__ __align__(16) bf16_t Pl[128 * 72];

    const bf16_t* Qhi = (const bf16_t*)(ws + OFF_PHI(0));
    const bf16_t* Qlo = (const bf16_t*)(ws + OFF_PLO(0));
    const bf16_t* Khi = (const bf16_t*)(ws + OFF_PHI(1));
    const bf16_t* Klo = (const bf16_t*)(ws + OFF_PLO(1));
    const bf16_t* Vhi = (const bf16_t*)(ws + OFF_PHI(2));
    const bf16_t* Vlo = (const bf16_t*)(ws + OFF_PLO(2));
    const bf16_t* Mb  = (const bf16_t*)(ws + OFF_MASKB);

    const int chunk = blockIdx.z;
    float* OP   = (float*)(ws + OFF_OP(chunk));                       // [bh*S+s][hd] fp32
    float* Mrow = (float*)(ws + OFF_ML + (size_t)chunk * 512 * 1024); // [bh*S+s]
    float* Lrow = Mrow + 64 * 1024;

    const int tid = threadIdx.x, lane = tid & 63, w = tid >> 6;
    const int fr = lane & 15, fg = lane >> 4;
    const int bh = blockIdx.y;
    const int q0 = blockIdx.x * 128;
    const int kStart = chunk * KCHUNK;
    const size_t qkBase = (size_t)bh * S_LEN * HD;
    const size_t vtBase = (size_t)bh * HD * S_LEN;

    // Q fragments (Q pre-scaled by 1/8 at projection epilogue)
    short8 qh[2][2], ql[2][2];
#pragma unroll
    for (int mf = 0; mf < 2; mf++) {
        const int qr = q0 + w * 32 + mf * 16 + fr;
#pragma unroll
        for (int kc = 0; kc < 2; kc++) {
            const size_t off = qkBase + (size_t)qr * HD + kc * 32 + fg * 8;
            qh[mf][kc] = ld8(Qhi + off);
            ql[mf][kc] = ld8(Qlo + off);
        }
    }

    f32x4 acco[2][4];
#pragma unroll
    for (int mf = 0; mf < 2; mf++)
#pragma unroll
        for (int df = 0; df < 4; df++) acco[mf][df] = f32x4{0.f, 0.f, 0.f, 0.f};
    float mrun[2][4], lrun[2][4];
#pragma unroll
    for (int mf = 0; mf < 2; mf++)
#pragma unroll
        for (int r = 0; r < 4; r++) { mrun[mf][r] = -__builtin_inff(); lrun[mf][r] = 0.f; }

#pragma unroll 1
    for (int kt = 0; kt < KCHUNK; kt += 64) {
        const int k0 = kStart + kt;
        // ---- scores: S = Q K^T (already scaled), split 3-MFMA, hd = 2 x K32
        f32x4 sacc[2][4];
#pragma unroll
        for (int mf = 0; mf < 2; mf++)
#pragma unroll
            for (int cf = 0; cf < 4; cf++) sacc[mf][cf] = f32x4{0.f, 0.f, 0.f, 0.f};
#pragma unroll
        for (int cf = 0; cf < 4; cf++) {
            const int kk = k0 + cf * 16 + fr;
#pragma unroll
            for (int kc = 0; kc < 2; kc++) {
                const size_t off = qkBase + (size_t)kk * HD + kc * 32 + fg * 8;
                const short8 kh = ld8(Khi + off);
                const short8 kl = ld8(Klo + off);
#pragma unroll
                for (int mf = 0; mf < 2; mf++) {
                    sacc[mf][cf] = mfma_bf16(qh[mf][kc], kh, sacc[mf][cf]);
                    sacc[mf][cf] = mfma_bf16(qh[mf][kc], kl, sacc[mf][cf]);
                    sacc[mf][cf] = mfma_bf16(ql[mf][kc], kh, sacc[mf][cf]);
                }
            }
        }

        // previous tile's PV ds_reads complete before overwriting P stripe
        asm volatile("s_waitcnt lgkmcnt(0)" ::: "memory");

        // ---- online softmax over FULL row (mask is post-softmax), then
        //      write masked P (hi/lo) into this wave's LDS stripe.
#pragma unroll
        for (int mf = 0; mf < 2; mf++) {
#pragma unroll
            for (int r = 0; r < 4; r++) {
                float mx = fmaxf(fmaxf(sacc[mf][0][r], sacc[mf][1][r]),
                                 fmaxf(sacc[mf][2][r], sacc[mf][3][r]));
                mx = fmaxf(mx, __shfl_xor(mx, 1, 64));
                mx = fmaxf(mx, __shfl_xor(mx, 2, 64));
                mx = fmaxf(mx, __shfl_xor(mx, 4, 64));
                mx = fmaxf(mx, __shfl_xor(mx, 8, 64));
                const float mnew = fmaxf(mrun[mf][r], mx);
                const float alpha = __expf(mrun[mf][r] - mnew);
                mrun[mf][r] = mnew;
                float psum = 0.f;
#pragma unroll
                for (int cf = 0; cf < 4; cf++) {
                    const float p = __expf(sacc[mf][cf][r] - mnew);
                    sacc[mf][cf][r] = p;
                    psum += p;
                }
                psum += __shfl_xor(psum, 1, 64);
                psum += __shfl_xor(psum, 2, 64);
                psum += __shfl_xor(psum, 4, 64);
                psum += __shfl_xor(psum, 8, 64);
                lrun[mf][r] = lrun[mf][r] * alpha + psum;
#pragma unroll
                for (int df = 0; df < 4; df++) acco[mf][df][r] *= alpha;

                const int qrl = w * 32 + mf * 16 + fg * 4 + r;
                const size_t mrow = (size_t)(q0 + qrl) * S_LEN + k0;
#pragma unroll
                for (int cf = 0; cf < 4; cf++) {
                    const int kcol = cf * 16 + fr;
                    const float mv = (float)Mb[mrow + kcol];      // {0,1}
                    const float pm = sacc[mf][cf][r] * mv;
                    const bf16_t h = (bf16_t)pm;
                    Ph[qrl * 72 + kcol] = h;
                    Pl[qrl * 72 + kcol] = (bf16_t)(pm - (float)h);
                }
            }
        }

        // P writes land before A-layout re-read (same wave, in-order DS)
        asm volatile("s_waitcnt lgkmcnt(0)" ::: "memory");

        // ---- PV accumulate: A = masked P (LDS), B = V^T (global, K-contig)
#pragma unroll
        for (int kc2 = 0; kc2 < 2; kc2++) {
            short8 pah[2], pal[2];
#pragma unroll
            for (int mf = 0; mf < 2; mf++) {
                const int prow = w * 32 + mf * 16 + fr;
                pah[mf] = ld8(&Ph[prow * 72 + kc2 * 32 + fg * 8]);
                pal[mf] = ld8(&Pl[prow * 72 + kc2 * 32 + fg * 8]);
            }
#pragma unroll
            for (int df = 0; df < 4; df++) {
                const size_t voff = vtBase + (size_t)(df * 16 + fr) * S_LEN + k0 + kc2 * 32 + fg * 8;
                const short8 vh = ld8(Vhi + voff);
                const short8 vl = ld8(Vlo + voff);
#pragma unroll
                for (int mf = 0; mf < 2; mf++) {
                    acco[mf][df] = mfma_bf16(pah[mf], vh, acco[mf][df]);
                    acco[mf][df] = mfma_bf16(pah[mf], vl, acco[mf][df]);
                    acco[mf][df] = mfma_bf16(pal[mf], vh, acco[mf][df]);
                }
            }
        }
    }

    // ---- epilogue: store UNNORMALIZED partial O (fp32) + per-row (m,l)
#pragma unroll
    for (int mf = 0; mf < 2; mf++) {
#pragma unroll
        for (int r = 0; r < 4; r++) {
            const int qrow = q0 + w * 32 + mf * 16 + fg * 4 + r;
            const size_t row = (size_t)bh * S_LEN + qrow;
            if (fr == 0) {        // identical across the 16-lane fr group
                Mrow[row] = mrun[mf][r];
                Lrow[row] = lrun[mf][r];
            }
#pragma unroll
            for (int df = 0; df < 4; df++)
                OP[(row << 6) + df * 16 + fr] = acco[mf][df][r];
        }
    }
}

// ---------------------------------------------------------------------------
// Merge NCHUNK partials: O = sum_c e^{m_c - m} O_c / sum_c e^{m_c - m} l_c,
// then split to bf16 hi/lo at the (dead) Q slot in [B,S,D] layout.
// ---------------------------------------------------------------------------
__global__ void merge_kernel(char* __restrict__ ws) {
    const int gid = blockIdx.x * blockDim.x + threadIdx.x;
    const int e0 = gid * 4;                       // 4 consecutive hd elements
    const int row = e0 >> 6;                      // bh*S + s
    const int d0 = e0 & 63;
    const int bh = row >> 11, s = row & (S_LEN - 1);

    const float* OP0 = (const float*)(ws + OFF_OP(0));
    const float* OP1 = (const float*)(ws + OFF_OP(1));
    const float* M0 = (const float*)(ws + OFF_ML);
    const float* L0 = M0 + 64 * 1024;
    const float* M1 = (const float*)(ws + OFF_ML + 512 * 1024);
    const float* L1 = M1 + 64 * 1024;
    bf16_t* Ohi = (bf16_t*)(ws + OFF_PHI(0));
    bf16_t* Olo = (bf16_t*)(ws + OFF_PLO(0));

    const float m0 = M0[row], m1 = M1[row];
    const float m = fmaxf(m0, m1);
    const float a0 = __expf(m0 - m), a1 = __expf(m1 - m);
    const float inv = 1.0f / (L0[row] * a0 + L1[row] * a1);

    const float4 o0 = *reinterpret_cast<const float4*>(OP0 + e0);
    const float4 o1 = *reinterpret_cast<const float4*>(OP1 + e0);
    float o[4] = {(o0.x * a0 + o1.x * a1) * inv, (o0.y * a0 + o1.y * a1) * inv,
                  (o0.z * a0 + o1.z * a1) * inv, (o0.w * a0 + o1.w * a1) * inv};

    const int b = bh >> 4, h = bh & (NH - 1);
    const size_t oidx = ((size_t)b * S_LEN + s) * DMODEL + h * HD + d0;
    ushort hb[4], lb[4];
#pragma unroll
    for (int j = 0; j < 4; j++) {
        bf16_t hh = (bf16_t)o[j];
        bf16_t ll = (bf16_t)(o[j] - (float)hh);
        hb[j] = __builtin_bit_cast(ushort, hh);
        lb[j] = __builtin_bit_cast(ushort, ll);
    }
    *reinterpret_cast<ushort4*>(Ohi + oidx) = ushort4{hb[0], hb[1], hb[2], hb[3]};
    *reinterpret_cast<ushort4*>(Olo + oidx) = ushort4{lb[0], lb[1], lb[2], lb[3]};
}

// ---------------------------------------------------------------------------
extern "C" void kernel_launch(void* const* d_in, const int* in_sizes, int n_in,
                              void* d_out, int out_size, void* d_ws, size_t ws_size,
                              hipStream_t stream) {
    (void)in_sizes; (void)n_in; (void)out_size;
    if (ws_size < WS_REQUIRED) return;  // clean incorrect-output signal, not an OOB crash

    const float* q    = (const float*)d_in[0];
    const float* k    = (const float*)d_in[1];
    const float* v    = (const float*)d_in[2];
    const int*   mask = (const int*)  d_in[3];
    const float* wq   = (const float*)d_in[4];
    const float* wk   = (const float*)d_in[5];
    const float* wv   = (const float*)d_in[6];
    const float* wout = (const float*)d_in[7];
    char* ws = (char*)d_ws;
    float* out = (float*)d_out;

    const size_t nX = (size_t)BATCH * S_LEN * DMODEL;  // 4,194,304
    const size_t nW = (size_t)DMODEL * DMODEL;         // 1,048,576
    const size_t nM = (size_t)S_LEN * S_LEN;           // 4,194,304
    const dim3 blk(256);

    // fp32 -> hi/lo splits
    cvt_split_kernel<<<dim3(nX / 1024), blk, 0, stream>>>(q, (bf16_t*)(ws + OFF_XHI(0)), (bf16_t*)(ws + OFF_XLO(0)), (int)nX);
    cvt_split_kernel<<<dim3(nX / 1024), blk, 0, stream>>>(k, (bf16_t*)(ws + OFF_XHI(1)), (bf16_t*)(ws + OFF_XLO(1)), (int)nX);
    cvt_split_kernel<<<dim3(nX / 1024), blk, 0, stream>>>(v, (bf16_t*)(ws + OFF_XHI(2)), (bf16_t*)(ws + OFF_XLO(2)), (int)nX);
    cvt_split_kernel<<<dim3(nW / 1024), blk, 0, stream>>>(wq,   (bf16_t*)(ws + OFF_WHI(0)), (bf16_t*)(ws + OFF_WLO(0)), (int)nW);
    cvt_split_kernel<<<dim3(nW / 1024), blk, 0, stream>>>(wk,   (bf16_t*)(ws + OFF_WHI(1)), (bf16_t*)(ws + OFF_WLO(1)), (int)nW);
    cvt_split_kernel<<<dim3(nW / 1024), blk, 0, stream>>>(wv,   (bf16_t*)(ws + OFF_WHI(2)), (bf16_t*)(ws + OFF_WLO(2)), (int)nW);
    cvt_split_kernel<<<dim3(nW / 1024), blk, 0, stream>>>(wout, (bf16_t*)(ws + OFF_WHI(3)), (bf16_t*)(ws + OFF_WLO(3)), (int)nW);

    // q/k/v projections (z = 0/1/2), head-split epilogues
    gemm_split_kernel<0><<<dim3(32, 8, 3), blk, 0, stream>>>(ws, nullptr);

    // mask -> bf16 {0,1} into region freed by the input splits (stream-ordered
    // after the projections, which are the last readers of that region)
    cvt_mask_kernel<<<dim3(nM / 1024), blk, 0, stream>>>(mask, (bf16_t*)(ws + OFF_MASKB), (int)nM);

    // flash attention, k-chunked (1024 blocks = 3-4/CU)
    attn_kernel<<<dim3(S_LEN / 128, BATCH * NH, NCHUNK), blk, 0, stream>>>(ws);

    // combine chunk partials -> O hi/lo (at the dead Q slot)
    merge_kernel<<<dim3(nX / 1024), blk, 0, stream>>>(ws);

    // output projection -> d_out (fp32)
    gemm_split_kernel<1><<<dim3(32, 8, 1), blk, 0, stream>>>(ws, out);
}